// Round 12
// baseline (399.028 us; speedup 1.0000x reference)
//
#include <hip/hip_runtime.h>
#include <math.h>

#define N_NODES 100000
#define N_EDGES 1200000
#define SCAN_BLOCKS ((N_NODES + 1023) / 1024)   // 98
#define LAYER_BLOCKS (N_NODES / 32)             // 3125: 8 waves, 4 nodes/wave

// ---------------------------------------------------------------- utilities

__device__ __forceinline__ float bcastf(float v, int l) {
    return __uint_as_float(__builtin_amdgcn_readlane(__float_as_uint(v), (unsigned)l));
}

__global__ __launch_bounds__(256) void zero_u32(unsigned* __restrict__ p, int n) {
    int i = blockIdx.x * 256 + threadIdx.x;
    if (i < n) p[i] = 0u;
}

// ---------------------------------------------------------------- CSR build
// 8 edges/thread (batched atomic chains — R11 win) + rank capture (no 2nd
// atomic pass). CSR = packed 4.8 MB index array (R7's 83 µs gather layout:
// index lines shared across nodes -> L2-resident on the gather's critical path).
__global__ __launch_bounds__(256) void hist8(const int* __restrict__ dst,
                                             unsigned* __restrict__ cnt,
                                             unsigned* __restrict__ rank) {
    const int base = blockIdx.x * 2048 + threadIdx.x;
    int dd[8]; bool ok[8];
#pragma unroll
    for (int t = 0; t < 8; ++t) {
        const int e = base + t * 256;
        ok[t] = e < N_EDGES;
        dd[t] = ok[t] ? dst[e] : 0;
    }
    unsigned r[8];
#pragma unroll
    for (int t = 0; t < 8; ++t)
        if (ok[t]) r[t] = atomicAdd(&cnt[dd[t]], 1u);
#pragma unroll
    for (int t = 0; t < 8; ++t)
        if (ok[t]) rank[base + t * 256] = r[t];
}

__global__ __launch_bounds__(256) void fill8(const int* __restrict__ src,
                                             const int* __restrict__ dst,
                                             const unsigned* __restrict__ rowptr,
                                             const unsigned* __restrict__ rank,
                                             unsigned* __restrict__ csr) {
    const int base = blockIdx.x * 2048 + threadIdx.x;
#pragma unroll
    for (int t = 0; t < 8; ++t) {
        const int e = base + t * 256;
        if (e < N_EDGES) {
            const int d = dst[e];
            csr[rowptr[d] + rank[e]] = (unsigned)src[e];
        }
    }
}

// R3-proven multi-block scan: partial -> bsum -> final (+invcnt)
__global__ __launch_bounds__(256) void scan_partial(const unsigned* __restrict__ cnt,
                                                    unsigned* __restrict__ pre,
                                                    unsigned* __restrict__ bsum) {
    __shared__ unsigned lds[256];
    const int t = threadIdx.x;
    const int base = blockIdx.x * 1024 + t * 4;
    unsigned v0 = 0, v1 = 0, v2 = 0, v3 = 0;
    if (base < N_NODES) {
        const uint4 q = *(const uint4*)(cnt + base);
        v0 = q.x; v1 = q.y; v2 = q.z; v3 = q.w;
    }
    const unsigned s = v0 + v1 + v2 + v3;
    lds[t] = s;
    __syncthreads();
    for (int off = 1; off < 256; off <<= 1) {
        unsigned u = (t >= off) ? lds[t - off] : 0u;
        __syncthreads();
        lds[t] += u;
        __syncthreads();
    }
    const unsigned excl = lds[t] - s;
    if (base < N_NODES) {
        uint4 o;
        o.x = excl;
        o.y = excl + v0;
        o.z = excl + v0 + v1;
        o.w = excl + v0 + v1 + v2;
        *(uint4*)(pre + base) = o;
    }
    if (t == 255) bsum[blockIdx.x] = lds[255];
}

__global__ __launch_bounds__(128) void scan_bsum(unsigned* __restrict__ bsum) {
    __shared__ unsigned lds[128];
    const int t = threadIdx.x;
    unsigned s = (t < SCAN_BLOCKS) ? bsum[t] : 0u;
    lds[t] = s;
    __syncthreads();
    for (int off = 1; off < 128; off <<= 1) {
        unsigned u = (t >= off) ? lds[t - off] : 0u;
        __syncthreads();
        lds[t] += u;
        __syncthreads();
    }
    if (t < SCAN_BLOCKS) bsum[t] = lds[t] - s;
}

__global__ __launch_bounds__(256) void scan_final(const unsigned* __restrict__ cnt,
                                                  const unsigned* __restrict__ pre,
                                                  const unsigned* __restrict__ bsum,
                                                  unsigned* __restrict__ rowptr,
                                                  float* __restrict__ invcnt) {
    const int t = threadIdx.x;
    const int base = blockIdx.x * 1024 + t * 4;
    if (base < N_NODES) {
        const unsigned off = bsum[blockIdx.x];
        uint4 p = *(const uint4*)(pre + base);
        const uint4 cq = *(const uint4*)(cnt + base);
        p.x += off; p.y += off; p.z += off; p.w += off;
        *(uint4*)(rowptr + base) = p;
        float4 ic;
        ic.x = 1.0f / (float)(cq.x + 1u);
        ic.y = 1.0f / (float)(cq.y + 1u);
        ic.z = 1.0f / (float)(cq.z + 1u);
        ic.w = 1.0f / (float)(cq.w + 1u);
        *(float4*)(invcnt + base) = ic;
    }
    if (blockIdx.x == 0 && t == 0) rowptr[N_NODES] = N_EDGES;
}

// ---------------------------------------------------------------- weight folding
// V2 = W @ U_bot [IN,64];  cp = c + b @ U_bot [64]
template <int IN>
__global__ __launch_bounds__(256) void precompute_v(const float* __restrict__ W,
                                                    const float* __restrict__ b,
                                                    const float* __restrict__ U,
                                                    const float* __restrict__ c,
                                                    float* __restrict__ V2,
                                                    float* __restrict__ cp) {
    __shared__ float Ub[64 * 64];
    const int tid = threadIdx.x;
    for (int j = tid; j < 64 * 64; j += 256) Ub[j] = U[IN * 64 + j];
    __syncthreads();
    const int w = tid >> 6, lane = tid & 63;
    const int r = blockIdx.x * 4 + w;
    if (r > IN) return;
    const float wv = (r < IN) ? W[r * 64 + lane] : b[lane];
    float o = (r < IN) ? 0.f : c[lane];
#pragma unroll 8
    for (int k = 0; k < 64; ++k) o += bcastf(wv, k) * Ub[k * 64 + lane];
    if (r < IN) V2[r * 64 + lane] = o;
    else        cp[lane] = o;
}

// ---------------------------------------------------------------- fused layer
// h[n,:] = relu( hp@Utop + m@V2 + cp ), m = mean(self + in-neighbors).
// Gather: R7's winning form — sequential per node, 8/4/1-deep lane loads,
// CSR-packed indices (rowptr/csr).
template <int IN, bool HEADS>
__global__ __launch_bounds__(512) void fused_layer(
        const float* __restrict__ hprev,
        const unsigned* __restrict__ csr,
        const unsigned* __restrict__ rowptr,
        const float* __restrict__ invcnt,
        const float* __restrict__ Utop,
        const float* __restrict__ V2,
        const float* __restrict__ cp,
        float* __restrict__ hnext,
        const float* __restrict__ Ws,  const float* __restrict__ bs,
        const float* __restrict__ Wst, const float* __restrict__ bst,
        const float* __restrict__ Wo,  const float* __restrict__ bo,
        float* __restrict__ state, float* __restrict__ part) {
    __shared__ float2 T[IN * 64];     // (Utop[k][lane], V2[k][lane])
    __shared__ float2 A2[32 * IN];    // (hp[k], m[k]) per local node
    __shared__ float red[8][2];
    const int tid = threadIdx.x;
    for (int j = tid; j < IN * 64; j += 512) T[j] = make_float2(Utop[j], V2[j]);
    const int wv = __builtin_amdgcn_readfirstlane(tid >> 6);   // uniform wave id
    const int lane = tid & 63;
    const int n0 = blockIdx.x * 32 + wv * 4;

    // ---- phase 1: gather-mean, 4 nodes sequential per wave, 8 loads deep
    for (int i = 0; i < 4; ++i) {
        const int n = n0 + i;
        const unsigned e1 = rowptr[n + 1];
        unsigned e = rowptr[n];
        const float hp = (lane < IN) ? hprev[(size_t)n * IN + lane] : 0.f;
        float m = hp;                                          // self loop
        for (; e + 8 <= e1; e += 8) {
            const unsigned i0 = csr[e + 0], i1 = csr[e + 1];
            const unsigned i2 = csr[e + 2], i3 = csr[e + 3];
            const unsigned i4 = csr[e + 4], i5 = csr[e + 5];
            const unsigned i6 = csr[e + 6], i7 = csr[e + 7];
            const float a0 = (lane < IN) ? hprev[(size_t)i0 * IN + lane] : 0.f;
            const float a1 = (lane < IN) ? hprev[(size_t)i1 * IN + lane] : 0.f;
            const float a2 = (lane < IN) ? hprev[(size_t)i2 * IN + lane] : 0.f;
            const float a3 = (lane < IN) ? hprev[(size_t)i3 * IN + lane] : 0.f;
            const float a4 = (lane < IN) ? hprev[(size_t)i4 * IN + lane] : 0.f;
            const float a5 = (lane < IN) ? hprev[(size_t)i5 * IN + lane] : 0.f;
            const float a6 = (lane < IN) ? hprev[(size_t)i6 * IN + lane] : 0.f;
            const float a7 = (lane < IN) ? hprev[(size_t)i7 * IN + lane] : 0.f;
            m += ((a0 + a1) + (a2 + a3)) + ((a4 + a5) + (a6 + a7));
        }
        for (; e + 4 <= e1; e += 4) {
            const unsigned i0 = csr[e + 0], i1 = csr[e + 1];
            const unsigned i2 = csr[e + 2], i3 = csr[e + 3];
            const float a0 = (lane < IN) ? hprev[(size_t)i0 * IN + lane] : 0.f;
            const float a1 = (lane < IN) ? hprev[(size_t)i1 * IN + lane] : 0.f;
            const float a2 = (lane < IN) ? hprev[(size_t)i2 * IN + lane] : 0.f;
            const float a3 = (lane < IN) ? hprev[(size_t)i3 * IN + lane] : 0.f;
            m += (a0 + a1) + (a2 + a3);
        }
        for (; e < e1; ++e) {
            const unsigned i0 = csr[e];
            m += (lane < IN) ? hprev[(size_t)i0 * IN + lane] : 0.f;
        }
        if (lane < IN) A2[(wv * 4 + i) * IN + lane] = make_float2(hp, m * invcnt[n]);
    }
    __syncthreads();

    // ---- phase 2: 4-node register-tile GEMM
    const float cpl = cp[lane];
    float acc0 = cpl, acc1 = cpl, acc2 = cpl, acc3 = cpl;
    const int ab = wv * 4 * IN;
#pragma unroll 8
    for (int k = 0; k < IN; ++k) {
        const float2 t = T[k * 64 + lane];
        const float2 a0 = A2[ab + k];               // uniform addr -> LDS broadcast
        const float2 a1 = A2[ab + IN + k];
        const float2 a2 = A2[ab + 2 * IN + k];
        const float2 a3 = A2[ab + 3 * IN + k];
        acc0 += a0.x * t.x + a0.y * t.y;
        acc1 += a1.x * t.x + a1.y * t.y;
        acc2 += a2.x * t.x + a2.y * t.y;
        acc3 += a3.x * t.x + a3.y * t.y;
    }
    const float h0 = fmaxf(acc0, 0.f), h1 = fmaxf(acc1, 0.f);
    const float h2 = fmaxf(acc2, 0.f), h3 = fmaxf(acc3, 0.f);
    const size_t o0 = (size_t)n0 * 64 + lane;
    hnext[o0]       = h0;
    hnext[o0 + 64]  = h1;
    hnext[o0 + 128] = h2;
    hnext[o0 + 192] = h3;

    // ---- optional fused heads (layer 3 only)
    if constexpr (HEADS) {
        const float ws0 = Ws[lane * 2], ws1 = Ws[lane * 2 + 1];
        const float wst = Wst[lane],    wo  = Wo[lane];
        float r[16];
        r[0]  = h0 * ws0; r[1]  = h0 * ws1; r[2]  = h0 * wst; r[3]  = h0 * wo;
        r[4]  = h1 * ws0; r[5]  = h1 * ws1; r[6]  = h1 * wst; r[7]  = h1 * wo;
        r[8]  = h2 * ws0; r[9]  = h2 * ws1; r[10] = h2 * wst; r[11] = h2 * wo;
        r[12] = h3 * ws0; r[13] = h3 * ws1; r[14] = h3 * wst; r[15] = h3 * wo;
#pragma unroll
        for (int off = 1; off < 64; off <<= 1)
#pragma unroll
            for (int t = 0; t < 16; ++t) r[t] += __shfl_xor(r[t], off);
        if (lane == 0) {
            const float bs0 = bs[0], bs1 = bs[1], bt = bst[0], b0 = bo[0];
            float sg = 0.f, oc = 0.f;
#pragma unroll
            for (int i = 0; i < 4; ++i) {
                const size_t n = (size_t)(n0 + i);
                state[n * 2 + 0] = r[i * 4 + 0] + bs0;
                state[n * 2 + 1] = r[i * 4 + 1] + bs1;
                sg += 1.0f / (1.0f + __expf(-(r[i * 4 + 2] + bt)));
                oc += r[i * 4 + 3] + b0;
            }
            red[wv][0] = sg; red[wv][1] = oc;
        }
        __syncthreads();
        if (tid == 0) {
            float a = 0.f, b2 = 0.f;
#pragma unroll
            for (int w = 0; w < 8; ++w) { a += red[w][0]; b2 += red[w][1]; }
            part[blockIdx.x * 2 + 0] = a;
            part[blockIdx.x * 2 + 1] = b2;
        }
    }
}

// ---------------------------------------------------------------- final reduce

__global__ __launch_bounds__(1024) void final_reduce(const float* __restrict__ part,
                                                     float* __restrict__ scal) {
    __shared__ float l0[1024], l1[1024];
    const int t = threadIdx.x;
    float a = 0.f, b = 0.f;
    for (int i = t; i < LAYER_BLOCKS; i += 1024) { a += part[2 * i]; b += part[2 * i + 1]; }
    l0[t] = a; l1[t] = b;
    __syncthreads();
    for (int off = 512; off; off >>= 1) {
        if (t < off) { l0[t] += l0[t + off]; l1[t] += l1[t + off]; }
        __syncthreads();
    }
    if (t == 0) {
        scal[0] = l0[0] / (float)N_NODES;   // stability
        scal[1] = l1[0] / (float)N_NODES;   // opf_cost
    }
}

// ---------------------------------------------------------------- launch

extern "C" void kernel_launch(void* const* d_in, const int* in_sizes, int n_in,
                              void* d_out, int out_size, void* d_ws, size_t ws_size,
                              hipStream_t stream) {
    const float* x   = (const float*)d_in[0];
    const int*   ei  = (const int*)d_in[1];
    const float* W1  = (const float*)d_in[2];
    const float* b1  = (const float*)d_in[3];
    const float* U1  = (const float*)d_in[4];
    const float* c1  = (const float*)d_in[5];
    const float* W2  = (const float*)d_in[6];
    const float* b2  = (const float*)d_in[7];
    const float* U2  = (const float*)d_in[8];
    const float* c2  = (const float*)d_in[9];
    const float* W3  = (const float*)d_in[10];
    const float* b3  = (const float*)d_in[11];
    const float* U3  = (const float*)d_in[12];
    const float* c3  = (const float*)d_in[13];
    const float* Ws  = (const float*)d_in[14];
    const float* bs  = (const float*)d_in[15];
    const float* Wst = (const float*)d_in[16];
    const float* bst = (const float*)d_in[17];
    const float* Wo  = (const float*)d_in[18];
    const float* bo  = (const float*)d_in[19];

    const int* src = ei;              // edge_index[0]
    const int* dst = ei + N_EDGES;    // edge_index[1]

    char* wsp = (char*)d_ws;
    size_t off = 0;
    auto alloc = [&](size_t bytes) -> char* {
        char* p = wsp + off;
        off = (off + bytes + 255) & ~(size_t)255;
        return p;
    };
    unsigned* cnt    = (unsigned*)alloc((size_t)N_NODES * 4);
    unsigned* rowptr = (unsigned*)alloc((size_t)(N_NODES + 1) * 4);
    float*    invcnt = (float*)   alloc((size_t)N_NODES * 4);
    unsigned* pre    = (unsigned*)alloc((size_t)N_NODES * 4);
    unsigned* bsum   = (unsigned*)alloc((size_t)SCAN_BLOCKS * 4);
    unsigned* rank   = (unsigned*)alloc((size_t)N_EDGES * 4);
    unsigned* csr    = (unsigned*)alloc((size_t)N_EDGES * 4);
    float*    part   = (float*)   alloc((size_t)LAYER_BLOCKS * 2 * 4);
    float*    V2a    = (float*)   alloc((size_t)5 * 64 * 4);
    float*    V2b    = (float*)   alloc((size_t)64 * 64 * 4);
    float*    V2c    = (float*)   alloc((size_t)64 * 64 * 4);
    float*    cpa    = (float*)   alloc((size_t)64 * 4);
    float*    cpb    = (float*)   alloc((size_t)64 * 4);
    float*    cpc    = (float*)   alloc((size_t)64 * 4);
    float*    hA     = (float*)   alloc((size_t)N_NODES * 64 * 4);
    float*    hB     = (float*)   alloc((size_t)N_NODES * 64 * 4);

    float* out   = (float*)d_out;
    float* state = out;                 // [N, 2]
    float* scal  = out + 200000;        // stability, opf_cost
    float* hout  = out + 200002;        // [N, 64]

    const int NB  = (N_NODES + 255) / 256;   // 391
    const int EB8 = (N_EDGES + 2047) / 2048; // 586

    // weight folding (graph-independent)
    precompute_v<5> <<<2, 256, 0, stream>>>(W1, b1, U1, c1, V2a, cpa);
    precompute_v<64><<<17, 256, 0, stream>>>(W2, b2, U2, c2, V2b, cpb);
    precompute_v<64><<<17, 256, 0, stream>>>(W3, b3, U3, c3, V2c, cpc);

    // CSR build: batched hist+rank -> scan -> batched fill (packed 4.8 MB csr)
    zero_u32<<<NB, 256, 0, stream>>>(cnt, N_NODES);
    hist8<<<EB8, 256, 0, stream>>>(dst, cnt, rank);
    scan_partial<<<SCAN_BLOCKS, 256, 0, stream>>>(cnt, pre, bsum);
    scan_bsum<<<1, 128, 0, stream>>>(bsum);
    scan_final<<<SCAN_BLOCKS, 256, 0, stream>>>(cnt, pre, bsum, rowptr, invcnt);
    fill8<<<EB8, 256, 0, stream>>>(src, dst, rowptr, rank, csr);

    // layers: h = relu(hp@Utop + mean@V2 + cp); heads fused into layer 3
    fused_layer<5, false><<<LAYER_BLOCKS, 512, 0, stream>>>(
        x, csr, rowptr, invcnt, U1, V2a, cpa, hA,
        nullptr, nullptr, nullptr, nullptr, nullptr, nullptr, nullptr, nullptr);
    fused_layer<64, false><<<LAYER_BLOCKS, 512, 0, stream>>>(
        hA, csr, rowptr, invcnt, U2, V2b, cpb, hB,
        nullptr, nullptr, nullptr, nullptr, nullptr, nullptr, nullptr, nullptr);
    fused_layer<64, true><<<LAYER_BLOCKS, 512, 0, stream>>>(
        hB, csr, rowptr, invcnt, U3, V2c, cpc, hout,
        Ws, bs, Wst, bst, Wo, bo, state, part);
    final_reduce<<<1, 1024, 0, stream>>>(part, scal);
}